// Round 4
// baseline (196.008 us; speedup 1.0000x reference)
//
#include <hip/hip_runtime.h>
#include <math.h>

#define NCLASS 1000
#define NCHUNK 250            // 1000 / 4 float4 chunks per row
#define WAVES_PER_BLOCK 4
#define BLOCK 256

// Round-4: zero-sync main. Round 3 (1 row/wave, 32 waves/CU) won 5us -> the
// kernel is latency-bound and TLP is the lever. Remaining serializers were the
// 16-wave __syncthreads convoy (all waves wait on the slowest D[arg,tgt]
// gather) and the thread-0 LDS epilogue. Now: 256-thr blocks, 1 row/wave, NO
// LDS, NO syncthreads -- each wave writes its term + D-slice max straight to
// ws and retires. 8 blocks/CU -> fine-grained backfill.
// Finalize reconstructs round-3's exact association (16 terms per group,
// ((a0+a1)+a2)+a3 over a_k=((c+c)+c)+c) -> bit-identical result.
__global__ __launch_bounds__(BLOCK, 8) void hce_main(
    const float* __restrict__ y_pred,
    const int*   __restrict__ y_true,
    const float* __restrict__ D,
    float* __restrict__ wsum,      // [0,nrows): per-row terms
    float* __restrict__ wmax,      // [0,nrows): per-wave D-slice maxes
    int nrows, int dsize)
{
    const int tid  = threadIdx.x;
    const int lane = tid & 63;
    const int wave = tid >> 6;
    const int row  = blockIdx.x * WAVES_PER_BLOCK + wave;

    // earliest load: target index (heads the dependent gather chain)
    int tgt = 0;
    if (lane == 0) tgt = y_true[row];

    // row payload: 4 float4 chunks per lane, coalesced 1KB/instr
    const float4* rp4 = (const float4*)(y_pred + (size_t)row * NCLASS);
    float4 v[4];
    #pragma unroll
    for (int t = 0; t < 4; ++t) {
        int c = lane + 64 * t;
        if (c < NCHUNK) v[t] = rp4[c];
    }

    // target logit (depends only on tgt; overlaps the butterflies)
    float xt = 0.0f;
    if (lane == 0) xt = y_pred[(size_t)row * NCLASS + tgt];

    // D-slice max: one element per thread max (stride nrows*64 = 2M > dsize)
    float dm = -1.0f;                      // D is uniform[0,1): nonnegative
    for (int i = row * 64 + lane; i < dsize; i += nrows * 64)
        dm = fmaxf(dm, D[i]);
    #pragma unroll
    for (int off = 32; off; off >>= 1)
        dm = fmaxf(dm, __shfl_xor(dm, off, 64));

    const int nt = (lane + 192 < NCHUNK) ? 4 : 3;

    // ---- phase 1: max + argmax (first occurrence == min col among ties) ----
    float m = -INFINITY; int arg = 0;
    #pragma unroll
    for (int t = 0; t < 4; ++t) {
        if (t < nt) {
            int col = 4 * (lane + 64 * t);
            if (v[t].x > m) { m = v[t].x; arg = col;     }
            if (v[t].y > m) { m = v[t].y; arg = col + 1; }
            if (v[t].z > m) { m = v[t].z; arg = col + 2; }
            if (v[t].w > m) { m = v[t].w; arg = col + 3; }
        }
    }
    #pragma unroll
    for (int off = 32; off; off >>= 1) {
        float om = __shfl_xor(m,   off, 64);
        int   oa = __shfl_xor(arg, off, 64);
        if (om > m || (om == m && oa < arg)) { m = om; arg = oa; }
    }

    // ---- phase 2: sum of exp(x - m) ----
    float s = 0.0f;
    #pragma unroll
    for (int t = 0; t < 4; ++t) {
        if (t < nt) {
            s += __expf(v[t].x - m) + __expf(v[t].y - m)
               + __expf(v[t].z - m) + __expf(v[t].w - m);
        }
    }
    #pragma unroll
    for (int off = 32; off; off >>= 1)
        s += __shfl_xor(s, off, 64);

    // ---- tail: one gather, two scalar stores, wave retires ----
    if (lane == 0) {
        float logp = xt - m - __logf(s);
        float d    = D[(size_t)arg * NCLASS + tgt];
        wsum[row] = logp * d;
        wmax[row] = dm;
    }
}

// Reconstructs round-3's partial[i] exactly: a_k = ((c0+c1)+c2)+c3 over 4
// consecutive rows, p_i = ((a0+a1)+a2)+a3 over the group of 16, then the
// identical strided accumulation + butterfly + 4-term combine.
__global__ __launch_bounds__(256) void hce_finalize(
    const float* __restrict__ wsum,
    const float* __restrict__ wmax,
    int ngroups,                   // nrows/16 = 2048
    float* __restrict__ out, float invB)
{
    const int tid  = threadIdx.x;
    const int lane = tid & 63;
    const int wave = tid >> 6;
    const float4* s4 = (const float4*)wsum;
    const float4* m4 = (const float4*)wmax;

    float s = 0.0f, mx = -1.0f;
    for (int i = tid; i < ngroups; i += 256) {
        float4 q0 = s4[4 * i + 0], q1 = s4[4 * i + 1];
        float4 q2 = s4[4 * i + 2], q3 = s4[4 * i + 3];
        float a0 = ((q0.x + q0.y) + q0.z) + q0.w;
        float a1 = ((q1.x + q1.y) + q1.z) + q1.w;
        float a2 = ((q2.x + q2.y) + q2.z) + q2.w;
        float a3 = ((q3.x + q3.y) + q3.z) + q3.w;
        s += ((a0 + a1) + a2) + a3;

        float4 r0 = m4[4 * i + 0], r1 = m4[4 * i + 1];
        float4 r2 = m4[4 * i + 2], r3 = m4[4 * i + 3];
        float b0 = fmaxf(fmaxf(r0.x, r0.y), fmaxf(r0.z, r0.w));
        float b1 = fmaxf(fmaxf(r1.x, r1.y), fmaxf(r1.z, r1.w));
        float b2 = fmaxf(fmaxf(r2.x, r2.y), fmaxf(r2.z, r2.w));
        float b3 = fmaxf(fmaxf(r3.x, r3.y), fmaxf(r3.z, r3.w));
        mx = fmaxf(mx, fmaxf(fmaxf(b0, b1), fmaxf(b2, b3)));
    }
    #pragma unroll
    for (int off = 32; off; off >>= 1) {
        s  += __shfl_xor(s, off, 64);
        mx  = fmaxf(mx, __shfl_xor(mx, off, 64));
    }
    __shared__ float ss[4], sm[4];
    if (lane == 0) { ss[wave] = s; sm[wave] = mx; }
    __syncthreads();
    if (tid == 0) {
        float S = ss[0] + ss[1] + ss[2] + ss[3];
        float M = fmaxf(fmaxf(sm[0], sm[1]), fmaxf(sm[2], sm[3]));
        out[0] = -S * invB / M;
    }
}

extern "C" void kernel_launch(void* const* d_in, const int* in_sizes, int n_in,
                              void* d_out, int out_size, void* d_ws, size_t ws_size,
                              hipStream_t stream) {
    const float* y_pred = (const float*)d_in[0];
    const int*   y_true = (const int*)  d_in[1];
    const float* D      = (const float*)d_in[2];
    // d_in[3] (fix_layer) is dead code in the reference.
    float* out = (float*)d_out;
    float* ws  = (float*)d_ws;

    const int B     = in_sizes[1];          // 32768 rows
    const int dsize = in_sizes[2];          // 1000*1000
    const int nb    = B / WAVES_PER_BLOCK;  // 8192 blocks

    float* wsum = ws;                       // [0, B)
    float* wmax = ws + B;                   // [B, 2B)

    hce_main<<<nb, BLOCK, 0, stream>>>(y_pred, y_true, D, wsum, wmax, B, dsize);
    hce_finalize<<<1, 256, 0, stream>>>(wsum, wmax, B / 16, out, 1.0f / (float)B);
}